// Round 15
// baseline (508.646 us; speedup 1.0000x reference)
//
#include <hip/hip_runtime.h>

#define TSTEPS 1024
#define CH 4               // chains per block (cols 0..3 of the MFMA tile)

typedef _Float16 half8  __attribute__((ext_vector_type(8)));
typedef float    f32x4  __attribute__((ext_vector_type(4)));

#define MFMA16(A_, B_, C_) __builtin_amdgcn_mfma_f32_16x16x32_f16((A_), (B_), (C_), 0, 0, 0)

__device__ __forceinline__ float fast_rcp(float x) { return __builtin_amdgcn_rcpf(x); }
__device__ __forceinline__ float fast_exp2(float x) {
#if __has_builtin(__builtin_amdgcn_exp2f)
    return __builtin_amdgcn_exp2f(x);
#else
    return exp2f(x);
#endif
}

// load 8 consecutive fp32, scale, convert to packed f16 MFMA fragment
__device__ __forceinline__ half8 load_w8s(const float* p, float s) {
    const float4 a = ((const float4*)p)[0];
    const float4 b = ((const float4*)p)[1];
    half8 r;
    r[0] = (_Float16)(s * a.x); r[1] = (_Float16)(s * a.y);
    r[2] = (_Float16)(s * a.z); r[3] = (_Float16)(s * a.w);
    r[4] = (_Float16)(s * b.x); r[5] = (_Float16)(s * b.y);
    r[6] = (_Float16)(s * b.z); r[7] = (_Float16)(s * b.w);
    return r;
}

// R14 + MFMA pipe rebalance + conflict-free scratch.
// R14 post-mortem: tick ~1010cyc; busiest SIMDs (w0+w4 / w1+w5) serialized
// 15 MFMAs (~285 pipe-cyc) while SIMD2/3 had 6. Fix: GRU2 goes LAG-2 and
// its x-part (W_ih2 @ h1, 6 MFMA/tile) moves to waves 2/3, which REUSE the
// B0/B1 h1-fragments they already read for GRU1. Waves 4/5 keep only the
// h-part (3 MFMA, must stay in the h2 recurrence's tick) + gate math.
// Pipe loads: 9/9/12/12 (max 228) vs 15/15/6/6 (max 285).
// Scratch stride 20->16 floats: (16c+u)%32 is 2-way everywhere (free, m136);
// the old +4 pad CAUSED 3-way read conflicts (26M counter in R14).
// Schedule (lag-2 GRU2):
//   tick t: w0..3 GRU1 step t (6 MFMA + 1 triple/lane, publish h1(t));
//           w2/3 also x-part(s=t-1) -> xsc[t&1]  (1<=t<=TSTEPS)
//           w4/5 GRU2 gates for s=t-2 (t>=2): h-part = W_hh2 @ h2(t-3)
//                (Bh from s_h2[(t+1)&1]) -> hsc (same-wave RT), x-part from
//                xsc[(t+1)&1] (written tick t-1, crossed one barrier),
//                1 triple/lane, publish h2(t-2) -> s_h2[t&1].
// One __syncthreads per tick; t runs to TSTEPS+1 to drain GRU2.
// MFMA layouts (m89/m120-verified): A[m=lane&15][k=quad*8+j],
// B[k=quad*8+j][n=lane&15], C/D: col(n)=lane&15, row(m)=quad*4+reg.
// exp2 pre-scaled gate math (r,z rows by -log2e; n rows by 2*log2e).
__global__ __launch_bounds__(384, 1)
void gru2_encoder(const float* __restrict__ x,
                  const float* __restrict__ W_ih1,
                  const float* __restrict__ W_hh1,
                  const float* __restrict__ b_ih1,
                  const float* __restrict__ b_hh1,
                  const float* __restrict__ W_ih2,
                  const float* __restrict__ W_hh2,
                  const float* __restrict__ b_ih2,
                  const float* __restrict__ b_hh2,
                  float* __restrict__ out)
{
    const int blk  = blockIdx.x;    // 256 blocks, CH chains each
    const int tid  = threadIdx.x;   // 384
    const int lane = tid & 63;
    const int wid  = tid >> 6;      // 0..5
    const int nl   = lane & 15;     // chain col (0..CH-1 real, rest dead)
    const int quad = lane >> 4;     // 0..3
    const int uu   = lane >> 2;     // redistributed unit-within-tile (0..15)
    const int cc   = lane & 3;      // redistributed chain (0..3)
    const int chain0 = blk * CH;

    const float SNEG = -1.44269504f;       // -log2(e)
    const float SP2  =  2.88539008f;       // 2*log2(e)

    __shared__ __align__(16) _Float16 s_h1[2][16][72];   // [par][chain][unit64+pad]
    __shared__ __align__(16) _Float16 s_h2[2][16][40];   // [par][chain][unit32+pad]
    __shared__ __align__(16) _Float16 s_x[TSTEPS][CH];   // x f16, [t][chain]
    __shared__ __align__(16) float sc1[4][3][CH][16];    // GRU1 preacts, per wave
    __shared__ __align__(16) float xsc[2][2][3][CH][16]; // GRU2 x-part [par][tile][gate]
    __shared__ __align__(16) float hsc[2][3][CH][16];    // GRU2 h-part [tile][gate]

    // ---- one-time staging
    for (int idx = tid; idx < CH * TSTEPS; idx += 384) {
        const int c = idx >> 10, t = idx & (TSTEPS - 1);
        s_x[t][c] = (_Float16)x[(size_t)(chain0 + c) * TSTEPS + t];
    }
    {
        _Float16* p1 = &s_h1[0][0][0];
        for (int idx = tid; idx < 2 * 16 * 72; idx += 384) p1[idx] = (_Float16)0.0f;
        _Float16* p2 = &s_h2[0][0][0];
        for (int idx = tid; idx < 2 * 16 * 40; idx += 384) p2[idx] = (_Float16)0.0f;
    }
    __syncthreads();

    if (wid < 4) {
        // ============ GRU1 unit-tile wid (+ GRU2 x-part on waves 2,3) ============
        const int U0 = wid * 16;
        const int ur = U0 + nl;
        const half8 aWr0 = load_w8s(W_hh1 + (size_t)(ur)       * 64 + quad * 8,      SNEG);
        const half8 aWr1 = load_w8s(W_hh1 + (size_t)(ur)       * 64 + 32 + quad * 8, SNEG);
        const half8 aWz0 = load_w8s(W_hh1 + (size_t)(64 + ur)  * 64 + quad * 8,      SNEG);
        const half8 aWz1 = load_w8s(W_hh1 + (size_t)(64 + ur)  * 64 + 32 + quad * 8, SNEG);
        const half8 aWn0 = load_w8s(W_hh1 + (size_t)(128 + ur) * 64 + quad * 8,      SP2);
        const half8 aWn1 = load_w8s(W_hh1 + (size_t)(128 + ur) * 64 + 32 + quad * 8, SP2);
        const int u4 = U0 + quad * 4;
        const float4 bir = *(const float4*)(b_ih1 + u4);
        const float4 bhr = *(const float4*)(b_hh1 + u4);
        const float4 biz = *(const float4*)(b_ih1 + 64 + u4);
        const float4 bhz = *(const float4*)(b_hh1 + 64 + u4);
        const float4 bhn = *(const float4*)(b_hh1 + 128 + u4);
        const f32x4 Cr = {SNEG*(bir.x+bhr.x), SNEG*(bir.y+bhr.y), SNEG*(bir.z+bhr.z), SNEG*(bir.w+bhr.w)};
        const f32x4 Cz = {SNEG*(biz.x+bhz.x), SNEG*(biz.y+bhz.y), SNEG*(biz.z+bhz.z), SNEG*(biz.w+bhz.w)};
        const f32x4 Cn = {SP2*bhn.x, SP2*bhn.y, SP2*bhn.z, SP2*bhn.w};
        const int ru = U0 + uu;
        const float twr = SNEG * W_ih1[ru];
        const float twz = SNEG * W_ih1[64 + ru];
        const float twn = SP2  * W_ih1[128 + ru];
        const float tbn = SP2  * b_ih1[128 + ru];

        // GRU2 x-part weights (waves 2,3 only; tile v = wid-2)
        const bool isx = (wid >= 2);
        const int v = wid - 2;
        half8 XiR0, XiR1, XiZ0, XiZ1, XiN0, XiN1;
        f32x4 Gr = {}, Gz = {}, Gnx = {};
        if (isx) {
            const int vr = v * 16 + nl;
            XiR0 = load_w8s(W_ih2 + (size_t)(vr)      * 64 + quad * 8,      SNEG);
            XiR1 = load_w8s(W_ih2 + (size_t)(vr)      * 64 + 32 + quad * 8, SNEG);
            XiZ0 = load_w8s(W_ih2 + (size_t)(32 + vr) * 64 + quad * 8,      SNEG);
            XiZ1 = load_w8s(W_ih2 + (size_t)(32 + vr) * 64 + 32 + quad * 8, SNEG);
            XiN0 = load_w8s(W_ih2 + (size_t)(64 + vr) * 64 + quad * 8,      SP2);
            XiN1 = load_w8s(W_ih2 + (size_t)(64 + vr) * 64 + 32 + quad * 8, SP2);
            const int v4 = v * 16 + quad * 4;
            const float4 b1 = *(const float4*)(b_ih2 + v4);
            const float4 b2 = *(const float4*)(b_hh2 + v4);
            const float4 b3 = *(const float4*)(b_ih2 + 32 + v4);
            const float4 b4 = *(const float4*)(b_hh2 + 32 + v4);
            const float4 b5 = *(const float4*)(b_ih2 + 64 + v4);
            Gr  = f32x4{SNEG*(b1.x+b2.x), SNEG*(b1.y+b2.y), SNEG*(b1.z+b2.z), SNEG*(b1.w+b2.w)};
            Gz  = f32x4{SNEG*(b3.x+b4.x), SNEG*(b3.y+b4.y), SNEG*(b3.z+b4.z), SNEG*(b3.w+b4.w)};
            Gnx = f32x4{SP2*b5.x, SP2*b5.y, SP2*b5.z, SP2*b5.w};
        }

        float h1s = 0.0f;   // h1[unit U0+uu][chain cc]
        for (int t = 0; t <= TSTEPS + 1; ++t) {
            const bool doG1 = (t < TSTEPS);
            const bool doX  = isx && (t >= 1) && (t <= TSTEPS);
            if (doG1 || doX) {
                const int pr = (t + 1) & 1;            // parity of h1(t-1)
                const half8 B0 = *(const half8*)&s_h1[pr][nl][quad * 8];
                const half8 B1 = *(const half8*)&s_h1[pr][nl][32 + quad * 8];
                if (doG1) {
                    f32x4 aR = MFMA16(aWr0, B0, Cr); aR = MFMA16(aWr1, B1, aR);
                    f32x4 aZ = MFMA16(aWz0, B0, Cz); aZ = MFMA16(aWz1, B1, aZ);
                    f32x4 aN = MFMA16(aWn0, B0, Cn); aN = MFMA16(aWn1, B1, aN);
                    if (nl < CH) {
                        *(f32x4*)&sc1[wid][0][nl][quad * 4] = aR;
                        *(f32x4*)&sc1[wid][1][nl][quad * 4] = aZ;
                        *(f32x4*)&sc1[wid][2][nl][quad * 4] = aN;
                    }
                }
                if (doX) {
                    // x-part of GRU2 step s=t-1 over h1(t-1) (same B0/B1)
                    f32x4 xR = MFMA16(XiR0, B0, Gr);  xR = MFMA16(XiR1, B1, xR);
                    f32x4 xZ = MFMA16(XiZ0, B0, Gz);  xZ = MFMA16(XiZ1, B1, xZ);
                    f32x4 xN = MFMA16(XiN0, B0, Gnx); xN = MFMA16(XiN1, B1, xN);
                    if (nl < CH) {
                        *(f32x4*)&xsc[t & 1][v][0][nl][quad * 4] = xR;
                        *(f32x4*)&xsc[t & 1][v][1][nl][quad * 4] = xZ;
                        *(f32x4*)&xsc[t & 1][v][2][nl][quad * 4] = xN;
                    }
                }
                if (doG1) {
                    // same-wave LDS write->read (lgkmcnt-ordered)
                    const float pR = sc1[wid][0][cc][uu];
                    const float pZ = sc1[wid][1][cc][uu];
                    const float pN = sc1[wid][2][cc][uu];
                    const float xv = (float)s_x[t][cc];
                    const float ea = fast_exp2(fmaf(twr, xv, pR));     // e^{-ar}
                    const float eb = fast_exp2(fmaf(twz, xv, pZ));     // e^{-az}
                    const float d1 = 1.0f + ea, d2 = 1.0f + eb;
                    const float inv = fast_rcp(d1 * d2);
                    const float r = d2 * inv, z = d1 * inv;
                    const float nx = fmaf(twn, xv, tbn);
                    const float ec = fast_exp2(fmaf(r, pN, nx));       // e^{2an}
                    const float nn = fmaf(-2.0f, fast_rcp(ec + 1.0f), 1.0f);
                    h1s = nn + z * (h1s - nn);
                    s_h1[t & 1][cc][ru] = (_Float16)h1s;               // cols>=CH stay 0
                }
            }
            __syncthreads();
        }
    } else {
        // ============ GRU2 h-part + gates, unit-tile v=wid-4, LAG 2 ============
        const int v  = wid - 4;
        const int V0 = v * 16;
        const int vr = V0 + nl;
        const half8 AhR = load_w8s(W_hh2 + (size_t)(vr)      * 32 + quad * 8, SNEG);
        const half8 AhZ = load_w8s(W_hh2 + (size_t)(32 + vr) * 32 + quad * 8, SNEG);
        const half8 AhN = load_w8s(W_hh2 + (size_t)(64 + vr) * 32 + quad * 8, SP2);
        const int v4 = V0 + quad * 4;
        const float4 bhn = *(const float4*)(b_hh2 + 64 + v4);
        const f32x4 ChN = {SP2*bhn.x, SP2*bhn.y, SP2*bhn.z, SP2*bhn.w};
        const f32x4 Zc  = {0.0f, 0.0f, 0.0f, 0.0f};

        float h2s = 0.0f;   // h2[unit V0+uu][chain cc]
        for (int t = 0; t <= TSTEPS + 1; ++t) {
            if (t >= 2) {
                // GRU2 step s=t-2: h-part over h2(t-3)
                const half8 Bh = *(const half8*)&s_h2[(t + 1) & 1][nl][quad * 8];
                f32x4 hR = MFMA16(AhR, Bh, Zc);
                f32x4 hZ = MFMA16(AhZ, Bh, Zc);
                f32x4 hN = MFMA16(AhN, Bh, ChN);
                if (nl < CH) {
                    *(f32x4*)&hsc[v][0][nl][quad * 4] = hR;
                    *(f32x4*)&hsc[v][1][nl][quad * 4] = hZ;
                    *(f32x4*)&hsc[v][2][nl][quad * 4] = hN;
                }
                // x-part written by wave (2+v) at tick t-1 (one barrier ago)
                const int xp = (t + 1) & 1;
                const float pR  = xsc[xp][v][0][cc][uu] + hsc[v][0][cc][uu];
                const float pZ  = xsc[xp][v][1][cc][uu] + hsc[v][1][cc][uu];
                const float pNx = xsc[xp][v][2][cc][uu];
                const float pNh = hsc[v][2][cc][uu];
                const float ea = fast_exp2(pR);
                const float eb = fast_exp2(pZ);
                const float d1 = 1.0f + ea, d2 = 1.0f + eb;
                const float inv = fast_rcp(d1 * d2);
                const float r2 = d2 * inv, z2 = d1 * inv;
                const float ec = fast_exp2(fmaf(r2, pNh, pNx));
                const float n2 = fmaf(-2.0f, fast_rcp(ec + 1.0f), 1.0f);
                h2s = n2 + z2 * (h2s - n2);
                s_h2[t & 1][cc][V0 + uu] = (_Float16)h2s;   // h2(t-2)
            }
            __syncthreads();
        }

        out[(size_t)(chain0 + cc) * 32 + V0 + uu] = h2s;
    }
}

extern "C" void kernel_launch(void* const* d_in, const int* in_sizes, int n_in,
                              void* d_out, int out_size, void* d_ws, size_t ws_size,
                              hipStream_t stream) {
    const float* x     = (const float*)d_in[0];
    const float* W_ih1 = (const float*)d_in[1];
    const float* W_hh1 = (const float*)d_in[2];
    const float* b_ih1 = (const float*)d_in[3];
    const float* b_hh1 = (const float*)d_in[4];
    const float* W_ih2 = (const float*)d_in[5];
    const float* W_hh2 = (const float*)d_in[6];
    const float* b_ih2 = (const float*)d_in[7];
    const float* b_hh2 = (const float*)d_in[8];
    float* out = (float*)d_out;

    gru2_encoder<<<dim3(1024 / CH), dim3(384), 0, stream>>>(
        x, W_ih1, W_hh1, b_ih1, b_hh1, W_ih2, W_hh2, b_ih2, b_hh2, out);
}

// Round 16
// 474.738 us; speedup vs baseline: 1.0714x; 1.0714x over previous
//
#include <hip/hip_runtime.h>

#define TSTEPS 1024
#define CH 4               // chains per block (cols 0..3 of the MFMA tile)

typedef _Float16 half8  __attribute__((ext_vector_type(8)));
typedef _Float16 half4v __attribute__((ext_vector_type(4)));
typedef float    f32x4  __attribute__((ext_vector_type(4)));

#define MFMA16(A_, B_, C_) __builtin_amdgcn_mfma_f32_16x16x32_f16((A_), (B_), (C_), 0, 0, 0)

__device__ __forceinline__ float fast_rcp(float x) { return __builtin_amdgcn_rcpf(x); }
__device__ __forceinline__ float fast_exp2(float x) {
#if __has_builtin(__builtin_amdgcn_exp2f)
    return __builtin_amdgcn_exp2f(x);
#else
    return exp2f(x);
#endif
}

// load 8 consecutive fp32, scale, convert to packed f16 MFMA fragment
__device__ __forceinline__ half8 load_w8s(const float* p, float s) {
    const float4 a = ((const float4*)p)[0];
    const float4 b = ((const float4*)p)[1];
    half8 r;
    r[0] = (_Float16)(s * a.x); r[1] = (_Float16)(s * a.y);
    r[2] = (_Float16)(s * a.z); r[3] = (_Float16)(s * a.w);
    r[4] = (_Float16)(s * b.x); r[5] = (_Float16)(s * b.y);
    r[6] = (_Float16)(s * b.z); r[7] = (_Float16)(s * b.w);
    return r;
}

// R14 structure EXACTLY, with one change: preact scratch stride 20 -> 16
// floats. R14's [20] stride made the redistribution READS 3-way on banks
// 0..3 (cc=1/3 rows wrap). With [16]: reads are cc 0/2 -> banks 0..15,
// cc 1/3 -> banks 16..31 (2-way, free per m136); b128 writes pair nl 0/2
// and 1/3 (2-way, free). R15's lag-2 rebalance regressed (469 vs 431 us
// typical) -- MFMA pipe imbalance was NOT the critical path; reverted.
//   waves 0..3: GRU1 unit-tile wid: 6 MFMA + 1 triple/lane (redistributed).
//   waves 4..5: GRU2 unit-tile, ONE STEP BEHIND: 9 MFMA + 1 triple/lane.
// One __syncthreads per tick. exp2 pre-scaled gate math (R10-validated).
// MFMA layouts (m89/m120-verified): A[m=lane&15][k=quad*8+j],
// B[k=quad*8+j][n=lane&15], C/D: col(n)=lane&15, row(m)=quad*4+reg.
// h-parity (R8 scheme): at tick t, h1(t-1) in s_h1[(t+1)&1]; GRU2 reads
// h2(t-2) from s_h2[t&1], writes h2(t-1) to s_h2[(t+1)&1].
// h-state cols CH..15 stay zero forever: dead MFMA columns compute zeros.
__global__ __launch_bounds__(384, 1)
void gru2_encoder(const float* __restrict__ x,
                  const float* __restrict__ W_ih1,
                  const float* __restrict__ W_hh1,
                  const float* __restrict__ b_ih1,
                  const float* __restrict__ b_hh1,
                  const float* __restrict__ W_ih2,
                  const float* __restrict__ W_hh2,
                  const float* __restrict__ b_ih2,
                  const float* __restrict__ b_hh2,
                  float* __restrict__ out)
{
    const int blk  = blockIdx.x;    // 256 blocks, CH chains each
    const int tid  = threadIdx.x;   // 384
    const int lane = tid & 63;
    const int wid  = tid >> 6;      // 0..5
    const int nl   = lane & 15;     // chain col (0..CH-1 real, rest dead)
    const int quad = lane >> 4;     // 0..3
    const int uu   = lane >> 2;     // redistributed unit-within-tile (0..15)
    const int cc   = lane & 3;      // redistributed chain (0..3)
    const int chain0 = blk * CH;

    const float SNEG = -1.44269504f;       // -log2(e)
    const float SP2  =  2.88539008f;       // 2*log2(e)

    __shared__ __align__(16) _Float16 s_h1[2][16][72];   // [par][chain][unit64+pad]
    __shared__ __align__(16) _Float16 s_h2[2][16][40];   // [par][chain][unit32+pad]
    __shared__ __align__(16) _Float16 s_x[TSTEPS][16];   // x f16, [t][chain] (cols>=CH zero)
    // per-wave preact scratch, stride 16 floats: 2-way banks on both the
    // b128 publishes (nl<CH) and the per-lane scalar reads -- free (m136)
    __shared__ __align__(16) float sc1[4][3][CH][16];    // GRU1 waves 0..3
    __shared__ __align__(16) float sc2[2][4][CH][16];    // GRU2 waves 4..5 (r,z,nx,nh)

    // ---- one-time staging: x cols 0..CH-1 from HBM, cols CH..15 zero
    for (int idx = tid; idx < 16 * TSTEPS; idx += 384) {
        const int m = idx >> 10, t = idx & (TSTEPS - 1);
        s_x[t][m] = (m < CH) ? (_Float16)x[(size_t)(chain0 + m) * TSTEPS + t]
                             : (_Float16)0.0f;
    }
    {
        _Float16* p1 = &s_h1[0][0][0];
        for (int idx = tid; idx < 2 * 16 * 72; idx += 384) p1[idx] = (_Float16)0.0f;
        _Float16* p2 = &s_h2[0][0][0];
        for (int idx = tid; idx < 2 * 16 * 40; idx += 384) p2[idx] = (_Float16)0.0f;
    }
    __syncthreads();

    if (wid < 4) {
        // ================= GRU1, unit-tile wid =================
        const int U0 = wid * 16;
        const int ur = U0 + nl;
        const half8 aWr0 = load_w8s(W_hh1 + (size_t)(ur)       * 64 + quad * 8,      SNEG);
        const half8 aWr1 = load_w8s(W_hh1 + (size_t)(ur)       * 64 + 32 + quad * 8, SNEG);
        const half8 aWz0 = load_w8s(W_hh1 + (size_t)(64 + ur)  * 64 + quad * 8,      SNEG);
        const half8 aWz1 = load_w8s(W_hh1 + (size_t)(64 + ur)  * 64 + 32 + quad * 8, SNEG);
        const half8 aWn0 = load_w8s(W_hh1 + (size_t)(128 + ur) * 64 + quad * 8,      SP2);
        const half8 aWn1 = load_w8s(W_hh1 + (size_t)(128 + ur) * 64 + 32 + quad * 8, SP2);
        // biases in MFMA C operand (per MFMA-layout lane: 4 units u4..u4+3)
        const int u4 = U0 + quad * 4;
        const float4 bir = *(const float4*)(b_ih1 + u4);
        const float4 bhr = *(const float4*)(b_hh1 + u4);
        const float4 biz = *(const float4*)(b_ih1 + 64 + u4);
        const float4 bhz = *(const float4*)(b_hh1 + 64 + u4);
        const float4 bhn = *(const float4*)(b_hh1 + 128 + u4);
        const f32x4 Cr = {SNEG*(bir.x+bhr.x), SNEG*(bir.y+bhr.y), SNEG*(bir.z+bhr.z), SNEG*(bir.w+bhr.w)};
        const f32x4 Cz = {SNEG*(biz.x+bhz.x), SNEG*(biz.y+bhz.y), SNEG*(biz.z+bhz.z), SNEG*(biz.w+bhz.w)};
        const f32x4 Cn = {SP2*bhn.x, SP2*bhn.y, SP2*bhn.z, SP2*bhn.w};
        // x-path scalars for this lane's ONE redistributed unit (U0+uu)
        const int ru = U0 + uu;
        const float twr = SNEG * W_ih1[ru];
        const float twz = SNEG * W_ih1[64 + ru];
        const float twn = SP2  * W_ih1[128 + ru];
        const float tbn = SP2  * b_ih1[128 + ru];

        float h1s = 0.0f;   // h1[unit U0+uu][chain cc]
        for (int t = 0; t <= TSTEPS; ++t) {
            if (t < TSTEPS) {
                const int pr = (t + 1) & 1;
                const half8 B0 = *(const half8*)&s_h1[pr][nl][quad * 8];
                const half8 B1 = *(const half8*)&s_h1[pr][nl][32 + quad * 8];
                f32x4 aR = MFMA16(aWr0, B0, Cr); aR = MFMA16(aWr1, B1, aR);
                f32x4 aZ = MFMA16(aWz0, B0, Cz); aZ = MFMA16(aWz1, B1, aZ);
                f32x4 aN = MFMA16(aWn0, B0, Cn); aN = MFMA16(aWn1, B1, aN);
                // intra-wave redistribution: cols 0..CH-1 publish f32x4 (units quad*4..+3)
                if (nl < CH) {
                    *(f32x4*)&sc1[wid][0][nl][quad * 4] = aR;
                    *(f32x4*)&sc1[wid][1][nl][quad * 4] = aZ;
                    *(f32x4*)&sc1[wid][2][nl][quad * 4] = aN;
                }
                // same-wave LDS write->read: compiler inserts lgkmcnt wait
                const float pR = sc1[wid][0][cc][uu];
                const float pZ = sc1[wid][1][cc][uu];
                const float pN = sc1[wid][2][cc][uu];
                const float xv = (float)s_x[t][cc];
                const float ea = fast_exp2(fmaf(twr, xv, pR));     // e^{-ar}
                const float eb = fast_exp2(fmaf(twz, xv, pZ));     // e^{-az}
                const float d1 = 1.0f + ea, d2 = 1.0f + eb;
                const float inv = fast_rcp(d1 * d2);
                const float r = d2 * inv, z = d1 * inv;
                const float nx = fmaf(twn, xv, tbn);
                const float ec = fast_exp2(fmaf(r, pN, nx));       // e^{2an}
                const float nn = fmaf(-2.0f, fast_rcp(ec + 1.0f), 1.0f);
                h1s = nn + z * (h1s - nn);
                s_h1[t & 1][cc][ru] = (_Float16)h1s;               // b16, cols>=CH untouched (stay 0)
            }
            __syncthreads();
        }
    } else {
        // ================= GRU2, unit-tile (wid-4), one step behind =================
        const int w2 = wid - 4;
        const int V0 = w2 * 16;
        const int vr = V0 + nl;
        const half8 AiR0 = load_w8s(W_ih2 + (size_t)(vr)      * 64 + quad * 8,      SNEG);
        const half8 AiR1 = load_w8s(W_ih2 + (size_t)(vr)      * 64 + 32 + quad * 8, SNEG);
        const half8 AiZ0 = load_w8s(W_ih2 + (size_t)(32 + vr) * 64 + quad * 8,      SNEG);
        const half8 AiZ1 = load_w8s(W_ih2 + (size_t)(32 + vr) * 64 + 32 + quad * 8, SNEG);
        const half8 AiN0 = load_w8s(W_ih2 + (size_t)(64 + vr) * 64 + quad * 8,      SP2);
        const half8 AiN1 = load_w8s(W_ih2 + (size_t)(64 + vr) * 64 + 32 + quad * 8, SP2);
        const half8 AhR = load_w8s(W_hh2 + (size_t)(vr)      * 32 + quad * 8,      SNEG);
        const half8 AhZ = load_w8s(W_hh2 + (size_t)(32 + vr) * 32 + quad * 8,      SNEG);
        const half8 AhN = load_w8s(W_hh2 + (size_t)(64 + vr) * 32 + quad * 8,      SP2);
        const int v4 = V0 + quad * 4;
        const float4 bir = *(const float4*)(b_ih2 + v4);
        const float4 bhr = *(const float4*)(b_hh2 + v4);
        const float4 biz = *(const float4*)(b_ih2 + 32 + v4);
        const float4 bhz = *(const float4*)(b_hh2 + 32 + v4);
        const float4 bin = *(const float4*)(b_ih2 + 64 + v4);
        const float4 bhn = *(const float4*)(b_hh2 + 64 + v4);
        const f32x4 Gr  = {SNEG*(bir.x+bhr.x), SNEG*(bir.y+bhr.y), SNEG*(bir.z+bhr.z), SNEG*(bir.w+bhr.w)};
        const f32x4 Gz  = {SNEG*(biz.x+bhz.x), SNEG*(biz.y+bhz.y), SNEG*(biz.z+bhz.z), SNEG*(biz.w+bhz.w)};
        const f32x4 Gnx = {SP2*bin.x, SP2*bin.y, SP2*bin.z, SP2*bin.w};
        const f32x4 Gnh = {SP2*bhn.x, SP2*bhn.y, SP2*bhn.z, SP2*bhn.w};

        float h2s = 0.0f;   // h2[unit V0+uu][chain cc]
        for (int t = 0; t <= TSTEPS; ++t) {
            if (t >= 1) {
                const int pA = (t + 1) & 1;            // parity of h1(t-1)
                const half8 B0 = *(const half8*)&s_h1[pA][nl][quad * 8];
                const half8 B1 = *(const half8*)&s_h1[pA][nl][32 + quad * 8];
                const half8 Bh = *(const half8*)&s_h2[t & 1][nl][quad * 8];   // h2(t-2)
                f32x4 aR = MFMA16(AiR0, B0, Gr);  aR = MFMA16(AiR1, B1, aR);
                aR = MFMA16(AhR, Bh, aR);
                f32x4 aZ = MFMA16(AiZ0, B0, Gz);  aZ = MFMA16(AiZ1, B1, aZ);
                aZ = MFMA16(AhZ, Bh, aZ);
                f32x4 aNx = MFMA16(AiN0, B0, Gnx); aNx = MFMA16(AiN1, B1, aNx);
                f32x4 aNh = MFMA16(AhN, Bh, Gnh);
                if (nl < CH) {
                    *(f32x4*)&sc2[w2][0][nl][quad * 4] = aR;
                    *(f32x4*)&sc2[w2][1][nl][quad * 4] = aZ;
                    *(f32x4*)&sc2[w2][2][nl][quad * 4] = aNx;
                    *(f32x4*)&sc2[w2][3][nl][quad * 4] = aNh;
                }
                const float pR  = sc2[w2][0][cc][uu];
                const float pZ  = sc2[w2][1][cc][uu];
                const float pNx = sc2[w2][2][cc][uu];
                const float pNh = sc2[w2][3][cc][uu];
                const float ea = fast_exp2(pR);
                const float eb = fast_exp2(pZ);
                const float d1 = 1.0f + ea, d2 = 1.0f + eb;
                const float inv = fast_rcp(d1 * d2);
                const float r2 = d2 * inv, z2 = d1 * inv;
                const float ec = fast_exp2(fmaf(r2, pNh, pNx));
                const float n2 = fmaf(-2.0f, fast_rcp(ec + 1.0f), 1.0f);
                h2s = n2 + z2 * (h2s - n2);
                s_h2[(t + 1) & 1][cc][V0 + uu] = (_Float16)h2s;   // h2(t-1)
            }
            __syncthreads();
        }

        // lane holds h2 for (unit V0+uu, chain cc)
        out[(size_t)(chain0 + cc) * 32 + V0 + uu] = h2s;
    }
}

extern "C" void kernel_launch(void* const* d_in, const int* in_sizes, int n_in,
                              void* d_out, int out_size, void* d_ws, size_t ws_size,
                              hipStream_t stream) {
    const float* x     = (const float*)d_in[0];
    const float* W_ih1 = (const float*)d_in[1];
    const float* W_hh1 = (const float*)d_in[2];
    const float* b_ih1 = (const float*)d_in[3];
    const float* b_hh1 = (const float*)d_in[4];
    const float* W_ih2 = (const float*)d_in[5];
    const float* W_hh2 = (const float*)d_in[6];
    const float* b_ih2 = (const float*)d_in[7];
    const float* b_hh2 = (const float*)d_in[8];
    float* out = (float*)d_out;

    gru2_encoder<<<dim3(1024 / CH), dim3(384), 0, stream>>>(
        x, W_ih1, W_hh1, b_ih1, b_hh1, W_ih2, W_hh2, b_ih2, b_hh2, out);
}